// Round 6
// baseline (1182.246 us; speedup 1.0000x reference)
//
#include <hip/hip_runtime.h>

// Problem constants
constexpr int B  = 64, S = 512, H = 768, WE = 4, ML = 5, D = 50, T = 21;
constexpr int NT = B * S;          // 32768 tokens
constexpr int HF = H + WE * D;     // 968 feature dim
constexpr int HP = 1024;           // padded feature dim (for clean float4 tiling)
constexpr int TPW = 2;             // tokens per wave in the logits kernel
constexpr float LOG2E = 1.4426950408889634f;
constexpr float LN2   = 0.6931471805599453f;

// ---------------------------------------------------------------------------
// Kernel 0: transpose + zero-pad W (968x21) -> Wp (21x1024): aligned float4.
// ---------------------------------------------------------------------------
__global__ void k_wprep(const float* __restrict__ W, float* __restrict__ Wp) {
  int idx = blockIdx.x * 256 + threadIdx.x;
  if (idx < T * HP) {
    int t = idx >> 10;
    int h = idx & (HP - 1);
    Wp[idx] = (h < HF) ? W[h * T + t] : 0.f;
  }
}

// ---------------------------------------------------------------------------
// Kernel 1: fused lexicon gather + weighted sum + concat + matvec + bias.
// One wave = 2 tokens. Register pressure controlled STRUCTURALLY (round-3
// lesson: launch_bounds(256,4) forced VGPR=64 -> 2 GB scratch traffic):
// no launch_bounds; sched_barrier(0) between 7-column groups stops the
// scheduler from hoisting all 21 Wp float4 loads at once.
// Peak live ~ 42 acc + 8 feat + 28 Wp + addr ~= 100 VGPR.
// ---------------------------------------------------------------------------
__global__ void k_logits(const float* __restrict__ seq,
                         const int*   __restrict__ ids,
                         const float* __restrict__ wts,
                         const float* __restrict__ emb,
                         const float* __restrict__ Wp,
                         const float* __restrict__ bias,
                         float* __restrict__ out) {
  __shared__ __align__(16) float lexs[4][TPW * 200];
  const int wave = threadIdx.x >> 6;
  const int lane = threadIdx.x & 63;
  const int tok0 = (blockIdx.x * 4 + wave) * TPW;

  // ---- lexicon: lex[k][w*50+d] = sum_l wts[tok,w,l] * emb[ids[tok,w,l], d]
  for (int o = lane; o < TPW * 200; o += 64) {
    int k = o / 200, r = o - k * 200;
    int w = r / 50,  d = r - w * 50;
    int base = ((tok0 + k) * WE + w) * ML;
    float a = 0.f;
#pragma unroll
    for (int l = 0; l < ML; ++l) {
      int   id = ids[base + l];
      float wt = wts[base + l];
      a += wt * emb[(long)id * D + d];
    }
    lexs[wave][o] = a;
  }
  __syncthreads();

  // ---- matvec: logits[tok][t] = sum_h feat[tok][h] * Wp[t][h]
  float acc0[T], acc1[T];
#pragma unroll
  for (int t = 0; t < T; ++t) { acc0[t] = 0.f; acc1[t] = 0.f; }

#pragma unroll
  for (int it = 0; it < 4; ++it) {
    const int h0 = it * 256 + lane * 4;
    float4 f0, f1;
    if (h0 < H) {
      f0 = *(const float4*)&seq[(long)(tok0 + 0) * H + h0];
      f1 = *(const float4*)&seq[(long)(tok0 + 1) * H + h0];
    } else if (h0 < HF) {
      f0 = *(const float4*)&lexs[wave][0 * 200 + (h0 - H)];
      f1 = *(const float4*)&lexs[wave][1 * 200 + (h0 - H)];
    } else {
      f0 = make_float4(0.f, 0.f, 0.f, 0.f);
      f1 = f0;
    }
#pragma unroll
    for (int tg = 0; tg < 3; ++tg) {
      __builtin_amdgcn_sched_barrier(0);   // cap Wp loads in flight to 7
#pragma unroll
      for (int t7 = 0; t7 < 7; ++t7) {
        const int t = tg * 7 + t7;
        float4 wv = *(const float4*)&Wp[t * HP + h0];
        acc0[t] += f0.x * wv.x + f0.y * wv.y + f0.z * wv.z + f0.w * wv.w;
        acc1[t] += f1.x * wv.x + f1.y * wv.y + f1.z * wv.z + f1.w * wv.w;
      }
    }
  }
  __builtin_amdgcn_sched_barrier(0);

  // ---- cross-lane reduce
#pragma unroll
  for (int t = 0; t < T; ++t) {
    float v0 = acc0[t], v1 = acc1[t];
#pragma unroll
    for (int m = 32; m; m >>= 1) {
      v0 += __shfl_xor(v0, m, 64);
      v1 += __shfl_xor(v1, m, 64);
    }
    acc0[t] = v0; acc1[t] = v1;
  }

  if (lane == 0) {
#pragma unroll
    for (int t = 0; t < T; ++t) {
      out[(long)(tok0 + 0) * T + t] = acc0[t] + bias[t];
      out[(long)(tok0 + 1) * T + t] = acc1[t] + bias[t];
    }
  }
}

// ---------------------------------------------------------------------------
// Kernel 2: CRF NLL per sequence (CONTROL this round — unchanged except OOB
// clamp for lane 63's unused emission load). One wave per b; lane j = lane%21
// holds alpha[j] in log2 domain; 3x7 split logsumexp; 4-chunk-deep emission
// pipeline in named registers.
// ---------------------------------------------------------------------------
__global__ void k_crf(const float* __restrict__ logits,
                      const int*   __restrict__ labels,
                      const int*   __restrict__ mask,
                      const float* __restrict__ start_t,
                      const float* __restrict__ end_t,
                      const float* __restrict__ trans,
                      float* __restrict__ part) {
  const int b = blockIdx.x;
  const int lane = threadIdx.x;       // block = 64 = 1 wave
  const long base = (long)b * S;
  const int j = lane % 21;
  int p = lane / 21; if (p == 3) p = 0;   // lane 63 duplicates lane 0
  const int i0 = p * 7;

  // TR[ii] = trans[i0+ii][j] * log2(e)  (base-2 domain)
  float TR[7];
#pragma unroll
  for (int ii = 0; ii < 7; ++ii) TR[ii] = trans[(i0 + ii) * T + j] * LOG2E;

  // ---- numerator (gold path), parallel over s + butterfly reduce
  float np = 0.f; int cnt = 0;
  for (int s = lane; s < S; s += 64) {
    int tg = labels[base + s];
    int mk = mask[base + s];
    cnt += mk;
    if (s == 0) {
      np += start_t[tg] + logits[base * T + tg];
    } else {
      int tp = labels[base + s - 1];
      np += mk ? (trans[tp * T + tg] + logits[(base + s) * T + tg]) : 0.f;
    }
  }
#pragma unroll
  for (int m = 32; m; m >>= 1) {
    np  += __shfl_xor(np, m, 64);
    cnt += __shfl_xor(cnt, m, 64);
  }
  int last = cnt - 1;
  int lt = labels[base + last];
  float num = np + end_t[lt];

  // ---- forward scan: chunks of 3 steps, 63 lanes load 3x21 emissions
  const int lq = lane / 21;                          // 0..3 (3 unused)
  const int lr = (lq < 3) ? (lane - 21 * lq) : 0;    // clamp lane 63 (OOB fix)
  const int lm = lane < 2 ? lane : 2;

#define CRF_LOAD(E, M, c) do {                                   \
    int _se = 1 + 3 * (c) + lq; if (_se > S - 1) _se = S - 1;    \
    E = logits[(base + _se) * T + lr];                           \
    int _sm = 1 + 3 * (c) + lm; if (_sm > S - 1) _sm = S - 1;    \
    M = mask[base + _sm];                                        \
  } while (0)

#define CRF_STEP(E, M, c, stp) do {                              \
    const int _s = 1 + 3 * (c) + (stp);                          \
    float en = __shfl(E, (stp) * 21 + j, 64);                    \
    int   mk = __shfl(M, (stp), 64);                             \
    float sh = __shfl(A, 0, 64);                                 \
    float p0 = exp2f(__shfl(A, i0 + 0, 64) + (TR[0] - sh));      \
    float p1 = exp2f(__shfl(A, i0 + 1, 64) + (TR[1] - sh));      \
    float p2 = exp2f(__shfl(A, i0 + 2, 64) + (TR[2] - sh));      \
    float p3 = exp2f(__shfl(A, i0 + 3, 64) + (TR[3] - sh));      \
    float p4 = exp2f(__shfl(A, i0 + 4, 64) + (TR[4] - sh));      \
    float p5 = exp2f(__shfl(A, i0 + 5, 64) + (TR[5] - sh));      \
    float p6 = exp2f(__shfl(A, i0 + 6, 64) + (TR[6] - sh));      \
    float ss = ((p0 + p1) + (p2 + p3)) + ((p4 + p5) + p6);       \
    float s1 = __shfl(ss, j, 64);                                \
    float s2 = __shfl(ss, j + 21, 64);                           \
    float s3 = __shfl(ss, j + 42, 64);                           \
    float An = fmaf(en, LOG2E, sh) + __log2f((s1 + s2) + s3);    \
    A = (mk && _s < S) ? An : A;                                 \
  } while (0)

#define CRF_STEP3(E, M, c) do { CRF_STEP(E, M, c, 0); CRF_STEP(E, M, c, 1); CRF_STEP(E, M, c, 2); } while (0)

  // alpha[j] in log2 domain
  float A = (start_t[j] + logits[base * T + j]) * LOG2E;

  float E0, E1, E2, E3; int M0, M1, M2, M3;
  CRF_LOAD(E0, M0, 0); CRF_LOAD(E1, M1, 1);
  CRF_LOAD(E2, M2, 2); CRF_LOAD(E3, M3, 3);

  // 172 chunks cover steps 1..516 (guarded); 43 groups x 4 chunks
  for (int g = 0; g < 43; ++g) {
    const int c = 4 * g;
    CRF_STEP3(E0, M0, c + 0); CRF_LOAD(E0, M0, c + 4);
    CRF_STEP3(E1, M1, c + 1); CRF_LOAD(E1, M1, c + 5);
    CRF_STEP3(E2, M2, c + 2); CRF_LOAD(E2, M2, c + 6);
    CRF_STEP3(E3, M3, c + 3); CRF_LOAD(E3, M3, c + 7);
  }
#undef CRF_LOAD
#undef CRF_STEP
#undef CRF_STEP3

  // ---- logZ = logsumexp_j(alpha[j] + end[j])  (back to ln domain)
  float a_ln = A * LN2;
  float y  = (lane < T) ? a_ln + end_t[lane] : -3e38f;
  float ym = y;
#pragma unroll
  for (int m = 32; m; m >>= 1) ym = fmaxf(ym, __shfl_xor(ym, m, 64));
  float z = (lane < T) ? exp2f((y - ym) * LOG2E) : 0.f;
#pragma unroll
  for (int m = 32; m; m >>= 1) z += __shfl_xor(z, m, 64);
  float logZ = ym + LN2 * __log2f(z);

  if (lane == 0) part[b] = logZ - num;
}

// ---------------------------------------------------------------------------
// Kernel 3: loss = sum_b part[b]
// ---------------------------------------------------------------------------
__global__ void k_loss(const float* __restrict__ part, float* __restrict__ out_loss) {
  int lane = threadIdx.x;
  float v = part[lane];                  // B == 64 exactly
#pragma unroll
  for (int m = 32; m; m >>= 1) v += __shfl_xor(v, m, 64);
  if (lane == 0) out_loss[0] = v;
}

// ---------------------------------------------------------------------------
extern "C" void kernel_launch(void* const* d_in, const int* in_sizes, int n_in,
                              void* d_out, int out_size, void* d_ws, size_t ws_size,
                              hipStream_t stream) {
  const float* seq  = (const float*)d_in[0];
  const int*   ids  = (const int*)  d_in[1];
  const float* wts  = (const float*)d_in[2];
  const int*   lbl  = (const int*)  d_in[3];
  const int*   msk  = (const int*)  d_in[4];
  const float* emb  = (const float*)d_in[5];
  const float* W    = (const float*)d_in[6];
  const float* bias = (const float*)d_in[7];
  const float* st   = (const float*)d_in[8];
  const float* en   = (const float*)d_in[9];
  const float* tr   = (const float*)d_in[10];

  float* out  = (float*)d_out;           // [NT*T logits][1 loss]
  float* Wp   = (float*)d_ws;            // 21*1024 floats
  float* part = Wp + T * HP;             // 64 floats

  k_wprep <<<(T * HP + 255) / 256, 256, 0, stream>>>(W, Wp);
  k_logits<<<NT / (4 * TPW), 256, 0, stream>>>(seq, ids, wts, emb, Wp, bias, out);
  k_crf   <<<B, 64, 0, stream>>>(out, lbl, msk, st, en, tr, part);
  k_loss  <<<1, 64, 0, stream>>>(part, out + (long)NT * T);
}

// Round 8
// 787.852 us; speedup vs baseline: 1.5006x; 1.5006x over previous
//
#include <hip/hip_runtime.h>

// Problem constants
constexpr int B  = 64, S = 512, H = 768, WE = 4, ML = 5, D = 50, T = 21;
constexpr int NT = B * S;          // 32768 tokens
constexpr int HF = H + WE * D;     // 968 feature dim
constexpr int HP = 1024;           // padded feature dim
constexpr float LOG2E = 1.4426950408889634f;
constexpr float LN2   = 0.6931471805599453f;

// ---------------------------------------------------------------------------
// Kernel 0: transpose + zero-pad W (968x21) -> Wp (21x1024): aligned float4.
// ---------------------------------------------------------------------------
__global__ void k_wprep(const float* __restrict__ W, float* __restrict__ Wp) {
  int idx = blockIdx.x * 256 + threadIdx.x;
  if (idx < T * HP) {
    int t = idx >> 10;
    int h = idx & (HP - 1);
    Wp[idx] = (h < HF) ? W[h * T + t] : 0.f;
  }
}

// ---------------------------------------------------------------------------
// Kernel A (path A): lexicon gather. One wave per (token, w); lanes 0..49 = d.
// ---------------------------------------------------------------------------
__global__ void k_lex(const int*   __restrict__ ids,
                      const float* __restrict__ wts,
                      const float* __restrict__ emb,
                      float*       __restrict__ lexb) {
  const int tok  = blockIdx.x;
  const int w    = threadIdx.x >> 6;
  const int lane = threadIdx.x & 63;
  if (lane >= D) return;
  const int ib = (tok * WE + w) * ML;
  float a = 0.f;
#pragma unroll
  for (int l = 0; l < ML; ++l) {
    int   id = ids[ib + l];
    float wt = wts[ib + l];
    a += wt * emb[(long)id * D + lane];
  }
  lexb[tok * (WE * D) + w * D + lane] = a;
}

// ---------------------------------------------------------------------------
// Matvec core shared by both paths. lexsrc points either at global lexb row
// block or at per-block LDS lex tile (stride 200 floats per token).
// __launch_bounds__(256,2): 256-VGPR budget ABOVE the ~140 demand — rounds
// 3/6 showed the allocator's occupancy heuristic spills accs (VGPR=64,
// 1.6-2.7 GB scratch traffic) unless pinned explicitly from above.
// ---------------------------------------------------------------------------
__device__ __forceinline__ void mv_core(const float* __restrict__ seq,
                                        const float* lex0, const float* lex1,
                                        const float* __restrict__ Wp,
                                        const float* __restrict__ bias,
                                        float* __restrict__ out,
                                        float* wtile, int tok0, int lane) {
  float acc0[T], acc1[T];
#pragma unroll
  for (int t = 0; t < T; ++t) { acc0[t] = 0.f; acc1[t] = 0.f; }

#pragma unroll
  for (int it = 0; it < 4; ++it) {
    __syncthreads();
#pragma unroll
    for (int rr = 0; rr < T; ++rr)
      wtile[rr * 256 + (threadIdx.x & 255)] = Wp[rr * HP + it * 256 + (threadIdx.x & 255)];
    __syncthreads();

    const int h0 = it * 256 + lane * 4;
    float4 f0, f1;
    if (h0 < H) {
      f0 = *(const float4*)&seq[(long)(tok0 + 0) * H + h0];
      f1 = *(const float4*)&seq[(long)(tok0 + 1) * H + h0];
    } else if (h0 < HF) {
      f0 = *(const float4*)&lex0[h0 - H];
      f1 = *(const float4*)&lex1[h0 - H];
    } else {
      f0 = make_float4(0.f, 0.f, 0.f, 0.f);
      f1 = f0;
    }
#pragma unroll
    for (int t = 0; t < T; ++t) {
      float4 wv = *(const float4*)&wtile[t * 256 + lane * 4];
      acc0[t] += f0.x * wv.x + f0.y * wv.y + f0.z * wv.z + f0.w * wv.w;
      acc1[t] += f1.x * wv.x + f1.y * wv.y + f1.z * wv.z + f1.w * wv.w;
    }
  }

#pragma unroll
  for (int t = 0; t < T; ++t) {
    float v0 = acc0[t], v1 = acc1[t];
#pragma unroll
    for (int m = 32; m; m >>= 1) {
      v0 += __shfl_xor(v0, m, 64);
      v1 += __shfl_xor(v1, m, 64);
    }
    acc0[t] = v0; acc1[t] = v1;
  }

  if (lane == 0) {
#pragma unroll
    for (int t = 0; t < T; ++t) {
      out[(long)(tok0 + 0) * T + t] = acc0[t] + bias[t];
      out[(long)(tok0 + 1) * T + t] = acc1[t] + bias[t];
    }
  }
}

__launch_bounds__(256, 2)
__global__ void k_mv(const float* __restrict__ seq,
                     const float* __restrict__ lexb,
                     const float* __restrict__ Wp,
                     const float* __restrict__ bias,
                     float*       __restrict__ out) {
  __shared__ __align__(16) float wtile[T * 256];   // 21.5 KB
  const int wave = threadIdx.x >> 6;
  const int lane = threadIdx.x & 63;
  const int tok0 = blockIdx.x * 8 + wave * 2;
  mv_core(seq, &lexb[(long)(tok0 + 0) * 200], &lexb[(long)(tok0 + 1) * 200],
          Wp, bias, out, wtile, tok0, lane);
}

// Path B: lexicon computed into LDS inside the matvec kernel (no big ws).
__launch_bounds__(256, 2)
__global__ void k_mv_fused(const float* __restrict__ seq,
                           const int*   __restrict__ ids,
                           const float* __restrict__ wts,
                           const float* __restrict__ emb,
                           const float* __restrict__ Wp,
                           const float* __restrict__ bias,
                           float*       __restrict__ out) {
  __shared__ __align__(16) float wtile[T * 256];   // 21.5 KB
  __shared__ __align__(16) float lexs[8 * 200];    // 6.4 KB
  const int wave = threadIdx.x >> 6;
  const int lane = threadIdx.x & 63;
  const int tokb = blockIdx.x * 8;

  for (int o = threadIdx.x; o < 8 * 200; o += 256) {
    int k = o / 200, r = o - k * 200;
    int w = r / 50,  d = r - w * 50;
    int ib = ((tokb + k) * WE + w) * ML;
    float a = 0.f;
#pragma unroll
    for (int l = 0; l < ML; ++l) {
      int   id = ids[ib + l];
      float wt = wts[ib + l];
      a += wt * emb[(long)id * D + d];
    }
    lexs[o] = a;
  }
  __syncthreads();

  const int tok0 = tokb + wave * 2;
  mv_core(seq, &lexs[(wave * 2 + 0) * 200], &lexs[(wave * 2 + 1) * 200],
          Wp, bias, out, wtile, tok0, lane);
}

// ---------------------------------------------------------------------------
// Kernel 2: CRF NLL. One wave per sequence. REPLICATED-ALPHA design: every
// lane holds all 21 alphas (static-indexed regs). Per step: lane k<21
// computes newA[k] fully IN-LANE (21 indep exp2 + tree sum, no cross-lane),
// then one 21-float LDS broadcast. Replaces ~15 serial ds_bpermutes/step
// (~1500 cy exposed at 1 wave/CU) with one LDS round-trip (~300 cy/step).
// ---------------------------------------------------------------------------
__global__ void k_crf(const float* __restrict__ logits,
                      const int*   __restrict__ labels,
                      const int*   __restrict__ mask,
                      const float* __restrict__ start_t,
                      const float* __restrict__ end_t,
                      const float* __restrict__ trans,
                      float* __restrict__ part) {
  __shared__ __align__(16) float xA[32];
  const int b = blockIdx.x;
  const int lane = threadIdx.x;            // block = 64 = 1 wave
  const long base = (long)b * S;
  const int kk = lane < T ? lane : 0;      // this lane's destination state

  // ---- numerator (gold path), parallel over s + butterfly reduce
  float np = 0.f; int cnt = 0;
  for (int s = lane; s < S; s += 64) {
    int tg = labels[base + s];
    int mk = mask[base + s];
    cnt += mk;
    if (s == 0) {
      np += start_t[tg] + logits[base * T + tg];
    } else {
      int tp = labels[base + s - 1];
      np += mk ? (trans[tp * T + tg] + logits[(base + s) * T + tg]) : 0.f;
    }
  }
#pragma unroll
  for (int m = 32; m; m >>= 1) {
    np  += __shfl_xor(np, m, 64);
    cnt += __shfl_xor(cnt, m, 64);
  }
  int last = cnt - 1;
  int lt = labels[base + last];
  float num = np + end_t[lt];

  // ---- per-lane transition column: TRcol[j] = trans[j][kk] * LOG2E
  float TRcol[T];
#pragma unroll
  for (int j = 0; j < T; ++j) TRcol[j] = trans[j * T + kk] * LOG2E;

  // ---- replicated alpha (log2 domain), every lane holds all 21
  float A[T];
#pragma unroll
  for (int j = 0; j < T; ++j)
    A[j] = (start_t[j] + logits[base * T + j]) * LOG2E;

#define CRF_LOADE(E, M, s_) do {                                  \
    int _ss = (s_) < (S - 1) ? (s_) : (S - 1);                    \
    E = logits[(base + _ss) * T + kk];                            \
    M = mask[base + _ss];                                         \
  } while (0)

#define CRF_STEP(E, M, s_) do {                                   \
    float sh = A[0];                                              \
    float p[T];                                                   \
    _Pragma("unroll")                                             \
    for (int j = 0; j < T; ++j)                                   \
      p[j] = exp2f(A[j] - sh + TRcol[j]);                         \
    float q0 = (p[0] + p[1])   + (p[2] + p[3]);                   \
    float q1 = (p[4] + p[5])   + (p[6] + p[7]);                   \
    float q2 = (p[8] + p[9])   + (p[10] + p[11]);                 \
    float q3 = (p[12] + p[13]) + (p[14] + p[15]);                 \
    float q4 = (p[16] + p[17]) + (p[18] + p[19]);                 \
    float sm = ((q0 + q1) + (q2 + q3)) + (q4 + p[20]);            \
    float nA = fmaf(E, LOG2E, sh + __log2f(sm));                  \
    if (lane < T) xA[lane] = nA;                                  \
    __asm__ volatile("s_waitcnt lgkmcnt(0)" ::: "memory");        \
    int mk = ((s_) <= S - 1) ? M : 0;                             \
    _Pragma("unroll")                                             \
    for (int j = 0; j < T; ++j) A[j] = mk ? xA[j] : A[j];         \
  } while (0)

  // emission prefetch: 8 named regs, 8 steps ahead
  float E0, E1, E2, E3, E4, E5, E6, E7;
  int   M0, M1, M2, M3, M4, M5, M6, M7;
  CRF_LOADE(E0, M0, 1); CRF_LOADE(E1, M1, 2);
  CRF_LOADE(E2, M2, 3); CRF_LOADE(E3, M3, 4);
  CRF_LOADE(E4, M4, 5); CRF_LOADE(E5, M5, 6);
  CRF_LOADE(E6, M6, 7); CRF_LOADE(E7, M7, 8);

  // 64 groups x 8 = steps 1..512 (step 512 guarded off)
  for (int g = 0; g < 64; ++g) {
    const int s = 1 + 8 * g;
    CRF_STEP(E0, M0, s + 0); CRF_LOADE(E0, M0, s + 8);
    CRF_STEP(E1, M1, s + 1); CRF_LOADE(E1, M1, s + 9);
    CRF_STEP(E2, M2, s + 2); CRF_LOADE(E2, M2, s + 10);
    CRF_STEP(E3, M3, s + 3); CRF_LOADE(E3, M3, s + 11);
    CRF_STEP(E4, M4, s + 4); CRF_LOADE(E4, M4, s + 12);
    CRF_STEP(E5, M5, s + 5); CRF_LOADE(E5, M5, s + 13);
    CRF_STEP(E6, M6, s + 6); CRF_LOADE(E6, M6, s + 14);
    CRF_STEP(E7, M7, s + 7); CRF_LOADE(E7, M7, s + 15);
  }
#undef CRF_LOADE
#undef CRF_STEP

  // ---- logZ = logsumexp_j(alpha[j] + end[j]); fully in-lane, all static
  float yv[T];
#pragma unroll
  for (int j = 0; j < T; ++j) yv[j] = A[j] * LN2 + end_t[j];
  float mx = yv[0];
#pragma unroll
  for (int j = 1; j < T; ++j) mx = fmaxf(mx, yv[j]);
  float sm = 0.f;
#pragma unroll
  for (int j = 0; j < T; ++j) sm += exp2f((yv[j] - mx) * LOG2E);
  float logZ = mx + LN2 * __log2f(sm);

  if (lane == 0) part[b] = logZ - num;
}

// ---------------------------------------------------------------------------
// Kernel 3: loss = sum_b part[b]
// ---------------------------------------------------------------------------
__global__ void k_loss(const float* __restrict__ part, float* __restrict__ out_loss) {
  int lane = threadIdx.x;
  float v = part[lane];                  // B == 64 exactly
#pragma unroll
  for (int m = 32; m; m >>= 1) v += __shfl_xor(v, m, 64);
  if (lane == 0) out_loss[0] = v;
}

// ---------------------------------------------------------------------------
extern "C" void kernel_launch(void* const* d_in, const int* in_sizes, int n_in,
                              void* d_out, int out_size, void* d_ws, size_t ws_size,
                              hipStream_t stream) {
  const float* seq  = (const float*)d_in[0];
  const int*   ids  = (const int*)  d_in[1];
  const float* wts  = (const float*)d_in[2];
  const int*   lbl  = (const int*)  d_in[3];
  const int*   msk  = (const int*)  d_in[4];
  const float* emb  = (const float*)d_in[5];
  const float* W    = (const float*)d_in[6];
  const float* bias = (const float*)d_in[7];
  const float* st   = (const float*)d_in[8];
  const float* en   = (const float*)d_in[9];
  const float* tr   = (const float*)d_in[10];

  float* out  = (float*)d_out;           // [NT*T logits][1 loss]
  float* Wp   = (float*)d_ws;            // 21*1024 floats
  float* part = Wp + T * HP;             // 64 floats
  float* lexb = part + 64;               // NT*200 floats = 26.2 MB (path A)

  const size_t need = ((size_t)T * HP + 64 + (size_t)NT * 200) * sizeof(float);
  const bool pathA = ws_size >= need;    // ws_size is fixed -> capture-stable

  k_wprep<<<(T * HP + 255) / 256, 256, 0, stream>>>(W, Wp);
  if (pathA) {
    k_lex<<<NT, 256, 0, stream>>>(ids, wts, emb, lexb);
    k_mv <<<NT / 8, 256, 0, stream>>>(seq, lexb, Wp, bias, out);
  } else {
    k_mv_fused<<<NT / 8, 256, 0, stream>>>(seq, ids, wts, emb, Wp, bias, out);
  }
  k_crf <<<B, 64, 0, stream>>>(out, lbl, msk, st, en, tr, part);
  k_loss<<<1, 64, 0, stream>>>(part, out + (long)NT * T);
}

// Round 9
// 598.587 us; speedup vs baseline: 1.9751x; 1.3162x over previous
//
#include <hip/hip_runtime.h>

// Problem constants
constexpr int B  = 64, S = 512, H = 768, WE = 4, ML = 5, D = 50, T = 21;
constexpr int NT = B * S;          // 32768 tokens
constexpr int HF = H + WE * D;     // 968 feature dim
constexpr int HP = 1024;           // padded feature dim
constexpr int TT = T * T;          // 441
constexpr float LOG2E = 1.4426950408889634f;
constexpr float LN2   = 0.6931471805599453f;

// ws layout (floats)
constexpr long WS_WP   = 0;                         // 21504
constexpr long WS_PART = WS_WP + (long)T * HP;      // 64
constexpr long WS_LEXB = WS_PART + 64;              // NT*200 floats
constexpr long LEXB_N  = (long)NT * 200;
constexpr long WS_NEED = (WS_LEXB + LEXB_N) * 4;    // 26.3 MB
constexpr long QN = (long)B * 128 * TT;             // M4-level floats

// ---------------------------------------------------------------------------
// Kernel 0: transpose + zero-pad W (968x21) -> Wp (21x1024): aligned float4.
// ---------------------------------------------------------------------------
__global__ void k_wprep(const float* __restrict__ W, float* __restrict__ Wp) {
  int idx = blockIdx.x * 256 + threadIdx.x;
  if (idx < T * HP) {
    int t = idx >> 10;
    int h = idx & (HP - 1);
    Wp[idx] = (h < HF) ? W[h * T + t] : 0.f;
  }
}

// ---------------------------------------------------------------------------
// Kernel A: lexicon gather. One wave per (token, w); lanes 0..49 = d.
// ---------------------------------------------------------------------------
__global__ void k_lex(const int*   __restrict__ ids,
                      const float* __restrict__ wts,
                      const float* __restrict__ emb,
                      float*       __restrict__ lexb) {
  const int tok  = blockIdx.x;
  const int w    = threadIdx.x >> 6;
  const int lane = threadIdx.x & 63;
  if (lane >= D) return;
  const int ib = (tok * WE + w) * ML;
  float a = 0.f;
#pragma unroll
  for (int l = 0; l < ML; ++l) {
    int   id = ids[ib + l];
    float wt = wts[ib + l];
    a += wt * emb[(long)id * D + lane];
  }
  lexb[tok * (WE * D) + w * D + lane] = a;
}

// ---------------------------------------------------------------------------
// Matvec core (wave = 2 tokens; Wp chunk staged in LDS per 256-h iteration).
// __launch_bounds__(256,2): 256-VGPR budget ABOVE the ~140 demand — rounds
// 3/6 showed the allocator's occupancy heuristic self-spills (VGPR=64,
// 1.6-2.7 GB scratch) unless the budget is pinned from above.
// ---------------------------------------------------------------------------
__device__ __forceinline__ void mv_core(const float* __restrict__ seq,
                                        const float* lex0, const float* lex1,
                                        const float* __restrict__ Wp,
                                        const float* __restrict__ bias,
                                        float* __restrict__ out,
                                        float* wtile, int tok0, int lane) {
  float acc0[T], acc1[T];
#pragma unroll
  for (int t = 0; t < T; ++t) { acc0[t] = 0.f; acc1[t] = 0.f; }

#pragma unroll
  for (int it = 0; it < 4; ++it) {
    __syncthreads();
#pragma unroll
    for (int rr = 0; rr < T; ++rr)
      wtile[rr * 256 + (threadIdx.x & 255)] = Wp[rr * HP + it * 256 + (threadIdx.x & 255)];
    __syncthreads();

    const int h0 = it * 256 + lane * 4;
    float4 f0, f1;
    if (h0 < H) {
      f0 = *(const float4*)&seq[(long)(tok0 + 0) * H + h0];
      f1 = *(const float4*)&seq[(long)(tok0 + 1) * H + h0];
    } else if (h0 < HF) {
      f0 = *(const float4*)&lex0[h0 - H];
      f1 = *(const float4*)&lex1[h0 - H];
    } else {
      f0 = make_float4(0.f, 0.f, 0.f, 0.f);
      f1 = f0;
    }
#pragma unroll
    for (int t = 0; t < T; ++t) {
      float4 wv = *(const float4*)&wtile[t * 256 + lane * 4];
      acc0[t] += f0.x * wv.x + f0.y * wv.y + f0.z * wv.z + f0.w * wv.w;
      acc1[t] += f1.x * wv.x + f1.y * wv.y + f1.z * wv.z + f1.w * wv.w;
    }
  }

#pragma unroll
  for (int t = 0; t < T; ++t) {
    float v0 = acc0[t], v1 = acc1[t];
#pragma unroll
    for (int m = 32; m; m >>= 1) {
      v0 += __shfl_xor(v0, m, 64);
      v1 += __shfl_xor(v1, m, 64);
    }
    acc0[t] = v0; acc1[t] = v1;
  }

  if (lane == 0) {
#pragma unroll
    for (int t = 0; t < T; ++t) {
      out[(long)(tok0 + 0) * T + t] = acc0[t] + bias[t];
      out[(long)(tok0 + 1) * T + t] = acc1[t] + bias[t];
    }
  }
}

__launch_bounds__(256, 2)
__global__ void k_mv(const float* __restrict__ seq,
                     const float* __restrict__ lexb,
                     const float* __restrict__ Wp,
                     const float* __restrict__ bias,
                     float*       __restrict__ out) {
  __shared__ __align__(16) float wtile[T * 256];
  const int wave = threadIdx.x >> 6;
  const int lane = threadIdx.x & 63;
  const int tok0 = blockIdx.x * 8 + wave * 2;
  mv_core(seq, &lexb[(long)(tok0 + 0) * 200], &lexb[(long)(tok0 + 1) * 200],
          Wp, bias, out, wtile, tok0, lane);
}

// Fallback (small ws): lexicon in LDS inside the matvec kernel.
__launch_bounds__(256, 2)
__global__ void k_mv_fused(const float* __restrict__ seq,
                           const int*   __restrict__ ids,
                           const float* __restrict__ wts,
                           const float* __restrict__ emb,
                           const float* __restrict__ Wp,
                           const float* __restrict__ bias,
                           float*       __restrict__ out) {
  __shared__ __align__(16) float wtile[T * 256];
  __shared__ __align__(16) float lexs[8 * 200];
  const int wave = threadIdx.x >> 6;
  const int lane = threadIdx.x & 63;
  const int tokb = blockIdx.x * 8;

  for (int o = threadIdx.x; o < 8 * 200; o += 256) {
    int k = o / 200, r = o - k * 200;
    int w = r / 50,  d = r - w * 50;
    int ib = ((tokb + k) * WE + w) * ML;
    float a = 0.f;
#pragma unroll
    for (int l = 0; l < ML; ++l) {
      int   id = ids[ib + l];
      float wt = wts[ib + l];
      a += wt * emb[(long)id * D + d];
    }
    lexs[o] = a;
  }
  __syncthreads();

  const int tok0 = tokb + wave * 2;
  mv_core(seq, &lexs[(wave * 2 + 0) * 200], &lexs[(wave * 2 + 1) * 200],
          Wp, bias, out, wtile, tok0, lane);
}

// ---------------------------------------------------------------------------
// Associative-scan CRF: (LSE,+)-semiring matrix products over time.
// COMPOSE21: out[i][k] = LSE_j(A[i][j]+B[j][k]), log2 domain; 441 outputs
// per wave, 7 rounds x 63 lanes. Masked steps = exact identity matrices.
// ---------------------------------------------------------------------------
#define COMPOSE21(Aptr, Bptr, STORE_EXPR)                          \
  do {                                                             \
    for (int r = 0; r < 7; ++r) {                                  \
      const int o = r * 63 + (lane < 63 ? lane : 62);              \
      const int ii = o / 21, kc = o - ii * 21;                     \
      const float* Ar = (Aptr) + ii * 21;                          \
      float mx = -3.0e38f;                                         \
      float vv[21];                                                \
      _Pragma("unroll")                                            \
      for (int j = 0; j < 21; ++j) {                               \
        vv[j] = Ar[j] + (Bptr)[j * 21 + kc];                       \
        mx = fmaxf(mx, vv[j]);                                     \
      }                                                            \
      float sum = 0.f;                                             \
      _Pragma("unroll")                                            \
      for (int j = 0; j < 21; ++j) sum += exp2f(vv[j] - mx);       \
      const float res = mx + __log2f(sum);                         \
      if (lane < 63) { STORE_EXPR; }                               \
    }                                                              \
  } while (0)

// k_quad: 4 elementary step-matrices -> M4. One wave per quad; 8192 waves.
// Covers steps 1..512 (512 = identity pad so 511 steps pair cleanly).
__launch_bounds__(256)
__global__ void k_quad(const float* __restrict__ logits,
                       const int*   __restrict__ mask,
                       const float* __restrict__ trans,
                       float*       __restrict__ dst) {
  __shared__ float trl[TT];
  __shared__ float wsm[4][6 * TT];
  const int wv = threadIdx.x >> 6, lane = threadIdx.x & 63;
  for (int o = threadIdx.x; o < TT; o += 256) trl[o] = trans[o] * LOG2E;
  __syncthreads();

  const int wid = blockIdx.x * 4 + wv;
  const int seq = wid >> 7, q = wid & 127;
  const long base = (long)seq * S;
  const int s0 = 1 + q * 4;

  float* E0 = &wsm[wv][0];
  float* E2 = E0 + 2 * TT;
  float* Pa = E0 + 4 * TT;
  float* Pb = E0 + 5 * TT;

  // stage the 4 emission rows (x LOG2E) into Pa[0..84)
  if (lane < T) {
#pragma unroll
    for (int s = 0; s < 4; ++s) {
      int ss = s0 + s;
      int mk = (ss < S) ? mask[base + ss] : 0;
      Pa[s * T + lane] = mk ? logits[(base + ss) * T + lane] * LOG2E : 0.f;
    }
  }
  // build elementary matrices E_s (identity when masked)
#pragma unroll
  for (int s = 0; s < 4; ++s) {
    int ss = s0 + s;
    int mk = (ss < S) ? mask[base + ss] : 0;
    float* Es = E0 + s * TT;
    for (int r = 0; r < 7; ++r) {
      int o = r * 63 + (lane < 63 ? lane : 62);
      int ii = o / 21, jj = o - ii * 21;
      float val = mk ? (trl[o] + Pa[s * T + jj]) : (ii == jj ? 0.f : -1e30f);
      if (lane < 63) Es[o] = val;
    }
  }
  COMPOSE21(E0, E0 + TT, Pb[o] = res);        // P01 = E0*E1
  COMPOSE21(E2, E2 + TT, Pa[o] = res);        // P23 = E2*E3 (e-data dead)
  COMPOSE21(Pb, Pa, E0[o] = res);             // M4 = P01*P23

  float* Dp = dst + (long)(seq * 128 + q) * TT;
  for (int o = lane; o < TT; o += 64) Dp[o] = E0[o];
}

// k_comp: one halving level: out[seq][m] = in[seq][2m] * in[seq][2m+1].
__launch_bounds__(256)
__global__ void k_comp(const float* __restrict__ src,
                       float* __restrict__ dst, int n_out, int lg) {
  __shared__ float ab[4][2 * TT];
  const int wv = threadIdx.x >> 6, lane = threadIdx.x & 63;
  const int wid = blockIdx.x * 4 + wv;
  const int seq = wid >> lg, m = wid & (n_out - 1);
  const float* A = src + ((long)seq * (n_out << 1) + (m << 1)) * TT;
  float* a0 = &ab[wv][0];
  for (int o = lane; o < 2 * TT; o += 64) a0[o] = A[o];
  float* Dp = dst + ((long)seq * n_out + m) * TT;
  COMPOSE21(a0, a0 + TT, Dp[o] = res);
}

// k_fin: numerator + alpha0*M_total + end -> part[b]. One wave per seq.
__global__ void k_fin(const float* __restrict__ logits,
                      const int*   __restrict__ labels,
                      const int*   __restrict__ mask,
                      const float* __restrict__ start_t,
                      const float* __restrict__ end_t,
                      const float* __restrict__ trans,
                      const float* __restrict__ Mfull,
                      float* __restrict__ part) {
  __shared__ float Ml[TT];
  const int b = blockIdx.x;
  const int lane = threadIdx.x;            // block = 64 = 1 wave
  const long base = (long)b * S;
  for (int o = lane; o < TT; o += 64) Ml[o] = Mfull[(long)b * TT + o];

  // numerator (gold path), parallel over s + butterfly reduce
  float np = 0.f; int cnt = 0;
  for (int s = lane; s < S; s += 64) {
    int tg = labels[base + s];
    int mk = mask[base + s];
    cnt += mk;
    if (s == 0) {
      np += start_t[tg] + logits[base * T + tg];
    } else {
      int tp = labels[base + s - 1];
      np += mk ? (trans[tp * T + tg] + logits[(base + s) * T + tg]) : 0.f;
    }
  }
#pragma unroll
  for (int m = 32; m; m >>= 1) {
    np  += __shfl_xor(np, m, 64);
    cnt += __shfl_xor(cnt, m, 64);
  }
  int last = cnt - 1;
  int lt = labels[base + last];
  float num = np + end_t[lt];

  // alpha0 (log2), replicated per lane
  float A0[T];
#pragma unroll
  for (int j = 0; j < T; ++j)
    A0[j] = (start_t[j] + logits[base * T + j]) * LOG2E;

  const int kk = lane < T ? lane : 0;
  float v[T]; float mx = -3.0e38f;
#pragma unroll
  for (int j = 0; j < T; ++j) { v[j] = A0[j] + Ml[j * 21 + kk]; mx = fmaxf(mx, v[j]); }
  float sm = 0.f;
#pragma unroll
  for (int j = 0; j < T; ++j) sm += exp2f(v[j] - mx);
  float aT = mx + __log2f(sm);             // log2 alpha_final[kk]

  float y  = (lane < T) ? aT * LN2 + end_t[lane] : -3.0e38f;
  float ym = y;
#pragma unroll
  for (int m = 32; m; m >>= 1) ym = fmaxf(ym, __shfl_xor(ym, m, 64));
  float z = (lane < T) ? exp2f((y - ym) * LOG2E) : 0.f;
#pragma unroll
  for (int m = 32; m; m >>= 1) z += __shfl_xor(z, m, 64);
  float logZ = ym + LN2 * __log2f(z);

  if (lane == 0) part[b] = logZ - num;
}

// ---------------------------------------------------------------------------
// Fallback sequential CRF (round-8 design; used only when ws is small).
// ---------------------------------------------------------------------------
__global__ void k_crf_seq(const float* __restrict__ logits,
                          const int*   __restrict__ labels,
                          const int*   __restrict__ mask,
                          const float* __restrict__ start_t,
                          const float* __restrict__ end_t,
                          const float* __restrict__ trans,
                          float* __restrict__ part) {
  __shared__ __align__(16) float xA[32];
  const int b = blockIdx.x;
  const int lane = threadIdx.x;
  const long base = (long)b * S;
  const int kk = lane < T ? lane : 0;

  float np = 0.f; int cnt = 0;
  for (int s = lane; s < S; s += 64) {
    int tg = labels[base + s];
    int mk = mask[base + s];
    cnt += mk;
    if (s == 0) {
      np += start_t[tg] + logits[base * T + tg];
    } else {
      int tp = labels[base + s - 1];
      np += mk ? (trans[tp * T + tg] + logits[(base + s) * T + tg]) : 0.f;
    }
  }
#pragma unroll
  for (int m = 32; m; m >>= 1) {
    np  += __shfl_xor(np, m, 64);
    cnt += __shfl_xor(cnt, m, 64);
  }
  int last = cnt - 1;
  int lt = labels[base + last];
  float num = np + end_t[lt];

  float TRcol[T];
#pragma unroll
  for (int j = 0; j < T; ++j) TRcol[j] = trans[j * T + kk] * LOG2E;

  float A[T];
#pragma unroll
  for (int j = 0; j < T; ++j)
    A[j] = (start_t[j] + logits[base * T + j]) * LOG2E;

#define CRF_LOADE(E, M, s_) do {                                  \
    int _ss = (s_) < (S - 1) ? (s_) : (S - 1);                    \
    E = logits[(base + _ss) * T + kk];                            \
    M = mask[base + _ss];                                         \
  } while (0)

#define CRF_STEP(E, M, s_) do {                                   \
    float sh = A[0];                                              \
    float p[T];                                                   \
    _Pragma("unroll")                                             \
    for (int j = 0; j < T; ++j)                                   \
      p[j] = exp2f(A[j] - sh + TRcol[j]);                         \
    float q0 = (p[0] + p[1])   + (p[2] + p[3]);                   \
    float q1 = (p[4] + p[5])   + (p[6] + p[7]);                   \
    float q2 = (p[8] + p[9])   + (p[10] + p[11]);                 \
    float q3 = (p[12] + p[13]) + (p[14] + p[15]);                 \
    float q4 = (p[16] + p[17]) + (p[18] + p[19]);                 \
    float sm = ((q0 + q1) + (q2 + q3)) + (q4 + p[20]);            \
    float nA = fmaf(E, LOG2E, sh + __log2f(sm));                  \
    if (lane < T) xA[lane] = nA;                                  \
    __asm__ volatile("s_waitcnt lgkmcnt(0)" ::: "memory");        \
    int mk = ((s_) <= S - 1) ? M : 0;                             \
    _Pragma("unroll")                                             \
    for (int j = 0; j < T; ++j) A[j] = mk ? xA[j] : A[j];         \
  } while (0)

  float E0, E1, E2, E3, E4, E5, E6, E7;
  int   M0, M1, M2, M3, M4, M5, M6, M7;
  CRF_LOADE(E0, M0, 1); CRF_LOADE(E1, M1, 2);
  CRF_LOADE(E2, M2, 3); CRF_LOADE(E3, M3, 4);
  CRF_LOADE(E4, M4, 5); CRF_LOADE(E5, M5, 6);
  CRF_LOADE(E6, M6, 7); CRF_LOADE(E7, M7, 8);

  for (int g = 0; g < 64; ++g) {
    const int s = 1 + 8 * g;
    CRF_STEP(E0, M0, s + 0); CRF_LOADE(E0, M0, s + 8);
    CRF_STEP(E1, M1, s + 1); CRF_LOADE(E1, M1, s + 9);
    CRF_STEP(E2, M2, s + 2); CRF_LOADE(E2, M2, s + 10);
    CRF_STEP(E3, M3, s + 3); CRF_LOADE(E3, M3, s + 11);
    CRF_STEP(E4, M4, s + 4); CRF_LOADE(E4, M4, s + 12);
    CRF_STEP(E5, M5, s + 5); CRF_LOADE(E5, M5, s + 13);
    CRF_STEP(E6, M6, s + 6); CRF_LOADE(E6, M6, s + 14);
    CRF_STEP(E7, M7, s + 7); CRF_LOADE(E7, M7, s + 15);
  }
#undef CRF_LOADE
#undef CRF_STEP

  float yv[T];
#pragma unroll
  for (int j = 0; j < T; ++j) yv[j] = A[j] * LN2 + end_t[j];
  float mx = yv[0];
#pragma unroll
  for (int j = 1; j < T; ++j) mx = fmaxf(mx, yv[j]);
  float sm = 0.f;
#pragma unroll
  for (int j = 0; j < T; ++j) sm += exp2f((yv[j] - mx) * LOG2E);
  float logZ = mx + LN2 * __log2f(sm);

  if (lane == 0) part[b] = logZ - num;
}

// ---------------------------------------------------------------------------
__global__ void k_loss(const float* __restrict__ part, float* __restrict__ out_loss) {
  int lane = threadIdx.x;
  float v = part[lane];
#pragma unroll
  for (int m = 32; m; m >>= 1) v += __shfl_xor(v, m, 64);
  if (lane == 0) out_loss[0] = v;
}

// ---------------------------------------------------------------------------
extern "C" void kernel_launch(void* const* d_in, const int* in_sizes, int n_in,
                              void* d_out, int out_size, void* d_ws, size_t ws_size,
                              hipStream_t stream) {
  const float* seq  = (const float*)d_in[0];
  const int*   ids  = (const int*)  d_in[1];
  const float* wts  = (const float*)d_in[2];
  const int*   lbl  = (const int*)  d_in[3];
  const int*   msk  = (const int*)  d_in[4];
  const float* emb  = (const float*)d_in[5];
  const float* W    = (const float*)d_in[6];
  const float* bias = (const float*)d_in[7];
  const float* st   = (const float*)d_in[8];
  const float* en   = (const float*)d_in[9];
  const float* tr   = (const float*)d_in[10];

  float* out  = (float*)d_out;
  float* ws   = (float*)d_ws;
  float* Wp   = ws + WS_WP;
  float* part = ws + WS_PART;
  float* lexb = ws + WS_LEXB;

  const bool big = ws_size >= (size_t)WS_NEED;

  k_wprep<<<(T * HP + 255) / 256, 256, 0, stream>>>(W, Wp);
  if (big) {
    k_lex<<<NT, 256, 0, stream>>>(ids, wts, emb, lexb);
    k_mv <<<NT / 8, 256, 0, stream>>>(seq, lexb, Wp, bias, out);
    // associative-scan CRF, ping-ponging in the now-dead lexb region
    float* pq = lexb;
    float* p1 = lexb + QN;
    k_quad<<<2048, 256, 0, stream>>>(out, msk, tr, pq);
    float* a = pq; float* c = p1;
    int lg = 6;
    for (int n = 64; n >= 1; n >>= 1) {
      k_comp<<<16 * n, 256, 0, stream>>>(a, c, n, lg);
      float* t2 = a; a = c; c = t2;
      --lg;
    }
    k_fin<<<B, 64, 0, stream>>>(out, lbl, msk, st, en, tr, a, part);
  } else {
    k_mv_fused<<<NT / 8, 256, 0, stream>>>(seq, ids, wts, emb, Wp, bias, out);
    k_crf_seq<<<B, 64, 0, stream>>>(out, lbl, msk, st, en, tr, part);
  }
  k_loss<<<1, 64, 0, stream>>>(part, out + (long)NT * T);
}